// Round 4
// baseline (814.617 us; speedup 1.0000x reference)
//
#include <hip/hip_runtime.h>

typedef unsigned short u16;
typedef __bf16 bf16x8 __attribute__((ext_vector_type(8)));
typedef float f32x4 __attribute__((ext_vector_type(4)));

__device__ __forceinline__ u16 f2bf(float f) {
  unsigned int u = __float_as_uint(f);
  u += 0x7fffu + ((u >> 16) & 1u);
  return (u16)(u >> 16);
}
__device__ __forceinline__ float bf2f(u16 v) {
  return __uint_as_float(((unsigned int)v) << 16);
}

// async global->LDS, 16B per lane. LDS dest must be wave-uniform base; HW adds lane*16.
__device__ __forceinline__ void gl_lds16(const u16* g, u16* l) {
  auto* lp = reinterpret_cast<__attribute__((address_space(3))) unsigned int*>(
      reinterpret_cast<uintptr_t>(l));
  auto* gp = reinterpret_cast<const __attribute__((address_space(1))) unsigned int*>(
      reinterpret_cast<uintptr_t>(g));
  __builtin_amdgcn_global_load_lds(gp, lp, 16, 0, 0);
}

// ---------------- fp32 -> bf16 convert ----------------
__global__ __launch_bounds__(256) void cvt_kernel(const float* __restrict__ in,
                                                  u16* __restrict__ out, int n4) {
  int i = blockIdx.x * 256 + threadIdx.x;
  if (i >= n4) return;
  float4 v = ((const float4*)in)[i];
  ushort4 o;
  o.x = f2bf(v.x); o.y = f2bf(v.y); o.z = f2bf(v.z); o.w = f2bf(v.w);
  ((ushort4*)out)[i] = o;
}

// ---------------- 256x256 8-phase bf16 GEMM, C[m][n] = sum_k A[m][k]*B[n][k] ----
// 8 waves (2M x 4N), per-wave 128x64 output. BK=64, 2 K-tiles per iteration,
// 128 KiB STATIC LDS double buffer (gfx950 addressable LDS/WG = 160 KiB).
// 16 MFMA per phase (one C-quadrant x K=64), counted vmcnt(4) only at phases
// 4/8 (never 0 in main loop), raw s_barrier phases, setprio around MFMA.
//
// LDS map (u16): buf b at b*32768: A tile [256 r][64 k] at +0, B at +16384.
// Row = 128 B = one bank wrap of 8 x 16B units. Swizzle: LDS[row][u'] =
// G[row][u' ^ (row&7)]; global_load_lds writes linearly, so the inverse
// permutation is applied on the per-lane GLOBAL source address, and every
// ds_read_b128 applies the same XOR. Quarter-wave reads land 2 lanes per
// 4-bank group in different wraps (2-way = free).

#define BARRIER() __builtin_amdgcn_s_barrier()
#define VMCNT(n_) asm volatile("s_waitcnt vmcnt(" #n_ ")" ::: "memory")
#define PH_SYNC()                                           \
  do {                                                      \
    BARRIER();                                              \
    asm volatile("s_waitcnt lgkmcnt(0)" ::: "memory");      \
    __builtin_amdgcn_sched_barrier(0);                      \
  } while (0)

#define STAGE_A(b_, h_, kt_)                                                        \
  do {                                                                              \
    gl_lds16(gA + (size_t)((h_) * 128) * K + (size_t)(kt_) * 64,                    \
             lds + (b_) * 32768 + (h_) * 8192 + w * 512);                           \
    gl_lds16(gA + (size_t)((h_) * 128 + 64) * K + (size_t)(kt_) * 64,               \
             lds + (b_) * 32768 + (h_) * 8192 + 4096 + w * 512);                    \
  } while (0)

#define STAGE_B(b_, h_, kt_)                                                        \
  do {                                                                              \
    gl_lds16(gB + (size_t)((h_) * 128) * K + (size_t)(kt_) * 64,                    \
             lds + (b_) * 32768 + 16384 + (h_) * 8192 + w * 512);                   \
    gl_lds16(gB + (size_t)((h_) * 128 + 64) * K + (size_t)(kt_) * 64,               \
             lds + (b_) * 32768 + 16384 + (h_) * 8192 + 4096 + w * 512);            \
  } while (0)

#define LOADS_A(b_, qm_)                                                            \
  do {                                                                              \
    _Pragma("unroll") for (int i2 = 0; i2 < 4; i2++) {                              \
      ar[i2][0] =                                                                   \
          *(const bf16x8*)&lds[(b_) * 32768 + abase + (qm_)*4096 + i2 * 1024 + ax0]; \
      ar[i2][1] =                                                                   \
          *(const bf16x8*)&lds[(b_) * 32768 + abase + (qm_)*4096 + i2 * 1024 + ax1]; \
    }                                                                               \
  } while (0)

#define LOADS_B(b_, qn_)                                                            \
  do {                                                                              \
    _Pragma("unroll") for (int j2 = 0; j2 < 2; j2++) {                              \
      br[(qn_)*2 + j2][0] =                                                         \
          *(const bf16x8*)&lds[(b_) * 32768 + bbase + (qn_)*2048 + j2 * 1024 + ax0]; \
      br[(qn_)*2 + j2][1] =                                                         \
          *(const bf16x8*)&lds[(b_) * 32768 + bbase + (qn_)*2048 + j2 * 1024 + ax1]; \
    }                                                                               \
  } while (0)

#define MFMA_Q(qm_, qn_)                                                            \
  do {                                                                              \
    __builtin_amdgcn_s_setprio(1);                                                  \
    _Pragma("unroll") for (int i2 = 0; i2 < 4; i2++) {                              \
      _Pragma("unroll") for (int j2 = 0; j2 < 2; j2++) {                            \
        acc[(qm_)*4 + i2][(qn_)*2 + j2] = __builtin_amdgcn_mfma_f32_16x16x32_bf16(  \
            ar[i2][0], br[(qn_)*2 + j2][0], acc[(qm_)*4 + i2][(qn_)*2 + j2], 0, 0, 0); \
        acc[(qm_)*4 + i2][(qn_)*2 + j2] = __builtin_amdgcn_mfma_f32_16x16x32_bf16(  \
            ar[i2][1], br[(qn_)*2 + j2][1], acc[(qm_)*4 + i2][(qn_)*2 + j2], 0, 0, 0); \
      }                                                                             \
    }                                                                               \
    __builtin_amdgcn_s_setprio(0);                                                  \
  } while (0)

template <int OUT_BF16>
__global__ __launch_bounds__(512, 2) void gemm8p(const u16* __restrict__ A,
                                                 const u16* __restrict__ B,
                                                 void* __restrict__ Cv,
                                                 int M, int N, int K) {
  __shared__ u16 lds[65536];  // 128 KiB: 2 bufs x (A 16K + B 16K) u16
  (void)M;
  const int t = threadIdx.x, lane = t & 63, w = t >> 6;
  const int col = lane & 15, quad = lane >> 4;
  const int wm = w >> 2, wn = w & 3;  // 2x4 wave grid

  // bijective XCD-aware block remap (m204 variant)
  const int nwg = gridDim.x * gridDim.y;
  const int wgid = blockIdx.y * gridDim.x + blockIdx.x;
  const int xcd = wgid & 7, lin = wgid >> 3;
  const int q8 = nwg >> 3, r8 = nwg & 7;
  const int nid = (xcd < r8 ? xcd * (q8 + 1) : r8 * (q8 + 1) + (xcd - r8) * q8) + lin;
  const int m0 = (nid / gridDim.x) * 256;
  const int n0 = (nid % gridDim.x) * 256;

  // staging: thread t writes LDS byte t*16 of a 64-row (8 KiB) segment:
  // row_local = t>>3, stored unit u' = t&7; unswizzled unit = (t&7)^((t>>3)&7).
  const int srow = t >> 3;
  const int sj = (t & 7) ^ (srow & 7);
  const u16* gA = A + (size_t)(m0 + srow) * K + sj * 8;
  const u16* gB = B + (size_t)(n0 + srow) * K + sj * 8;

  // fragment-read bases (u16 units). Frag row = rbase + col (rbase mult of 16,
  // so row&7 = col&7); k-half kh unit = kh*4 + quad, swizzled ^= (col&7).
  const int abase = wm * 8192 + col * 64;
  const int bbase = 16384 + wn * 4096 + col * 64;
  const int ax0 = ((quad ^ (col & 7)) << 3);
  const int ax1 = (((4 + quad) ^ (col & 7)) << 3);

  f32x4 acc[8][4] = {};
  bf16x8 ar[4][2], br[4][2];  // br[0..1]=qn0, br[2..3]=qn1

  // prologue: tile0 -> buf0 (A,B), tile1.B -> buf1; wait tile0 (leave 4 ops in flight)
  STAGE_A(0, 0, 0); STAGE_A(0, 1, 0);
  STAGE_B(0, 0, 0); STAGE_B(0, 1, 0);
  STAGE_B(1, 0, 1); STAGE_B(1, 1, 1);
  VMCNT(4);
  BARRIER();

  const int NIT = K >> 7;  // 2 K-tiles (128 k) per iteration
  for (int it = 0; it < NIT - 1; ++it) {
    const int kt = it * 2;
    // P1: buf0 quadrant (0,0); stage buf1.Ah0 <- tile kt+1
    LOADS_A(0, 0); LOADS_B(0, 0);
    STAGE_A(1, 0, kt + 1);
    PH_SYNC(); MFMA_Q(0, 0); BARRIER();
    // P2: buf0 (0,1); stage buf1.Ah1
    LOADS_B(0, 1);
    STAGE_A(1, 1, kt + 1);
    PH_SYNC(); MFMA_Q(0, 1); BARRIER();
    // P3: buf0 (1,0); stage buf0.Bh0 <- tile kt+2
    LOADS_A(0, 1);
    STAGE_B(0, 0, kt + 2);
    PH_SYNC(); MFMA_Q(1, 0); BARRIER();
    // P4: buf0 (1,1); stage buf0.Bh1; drain to 4 -> buf1 tile kt+1 resident
    STAGE_B(0, 1, kt + 2);
    PH_SYNC(); MFMA_Q(1, 1); VMCNT(4); BARRIER();
    // P5: buf1 (0,0); stage buf0.Ah0 <- tile kt+2
    LOADS_A(1, 0); LOADS_B(1, 0);
    STAGE_A(0, 0, kt + 2);
    PH_SYNC(); MFMA_Q(0, 0); BARRIER();
    // P6: buf1 (0,1); stage buf0.Ah1
    LOADS_B(1, 1);
    STAGE_A(0, 1, kt + 2);
    PH_SYNC(); MFMA_Q(0, 1); BARRIER();
    // P7: buf1 (1,0); stage buf1.Bh0 <- tile kt+3
    LOADS_A(1, 1);
    STAGE_B(1, 0, kt + 3);
    PH_SYNC(); MFMA_Q(1, 0); BARRIER();
    // P8: buf1 (1,1); stage buf1.Bh1; drain to 4 -> buf0 tile kt+2 resident
    STAGE_B(1, 1, kt + 3);
    PH_SYNC(); MFMA_Q(1, 1); VMCNT(4); BARRIER();
  }

  // epilogue: tiles 2*NIT-2 (buf0, resident), 2*NIT-1 (buf1: B staged, stage A now)
  {
    const int kl = 2 * NIT - 1;
    LOADS_A(0, 0); LOADS_B(0, 0);
    STAGE_A(1, 0, kl);
    PH_SYNC(); MFMA_Q(0, 0); BARRIER();
    LOADS_B(0, 1);
    STAGE_A(1, 1, kl);
    PH_SYNC(); MFMA_Q(0, 1); BARRIER();
    LOADS_A(0, 1);
    PH_SYNC(); MFMA_Q(1, 0); BARRIER();
    PH_SYNC(); MFMA_Q(1, 1); VMCNT(0); BARRIER();
    LOADS_A(1, 0); LOADS_B(1, 0);
    PH_SYNC(); MFMA_Q(0, 0); BARRIER();
    LOADS_B(1, 1);
    PH_SYNC(); MFMA_Q(0, 1); BARRIER();
    LOADS_A(1, 1);
    PH_SYNC(); MFMA_Q(1, 0); BARRIER();
    MFMA_Q(1, 1);
  }

  // C write: col = lane&15 (n side), row = quad*4 + reg (m side)
#pragma unroll
  for (int i = 0; i < 8; i++) {
#pragma unroll
    for (int j = 0; j < 4; j++) {
      const int mb = m0 + wm * 128 + i * 16 + quad * 4;
      const int n = n0 + wn * 64 + j * 16 + col;
#pragma unroll
      for (int r = 0; r < 4; r++) {
        float v = acc[i][j][r];
        if constexpr (OUT_BF16)
          ((u16*)Cv)[(size_t)(mb + r) * N + n] = f2bf(v);
        else
          ((float*)Cv)[(size_t)(mb + r) * N + n] = v;
      }
    }
  }
}

// ---------------- 64x64-tiled u16 transpose: out[c][r] = in[r][c] ----------------
__global__ __launch_bounds__(256) void transpose_kernel(const u16* __restrict__ in,
                                                        u16* __restrict__ out,
                                                        int in_stride, int out_stride) {
  __shared__ u16 tile[64][72];
  const int t = threadIdx.x;
  const int bm = blockIdx.y;  // input row tile
  const int bn = blockIdx.x;  // input col tile
  const int r = t >> 3, c = (t & 7) * 8;
  const u16* src = in + (size_t)(bm * 64 + r) * in_stride + bn * 64 + c;
  *(uint4*)&tile[r][c] = *(const uint4*)src;
  *(uint4*)&tile[r + 32][c] = *(const uint4*)(src + (size_t)32 * in_stride);
  __syncthreads();
  u16 vals[8];
  u16* dst = out + (size_t)(bn * 64 + r) * out_stride + bm * 64 + c;
#pragma unroll
  for (int i = 0; i < 8; i++) vals[i] = tile[c + i][r];
  *(uint4*)dst = *(uint4*)vals;
#pragma unroll
  for (int i = 0; i < 8; i++) vals[i] = tile[c + i][r + 32];
  *(uint4*)(dst + (size_t)32 * out_stride) = *(uint4*)vals;
}

// ---------------- Llama-3.1 RoPE (rotate-half, non-interleaved) ----------------
__global__ __launch_bounds__(256) void rope_kernel(u16* __restrict__ X,
                                                   const int* __restrict__ pos_ids,
                                                   int log2H, int row_stride) {
  int tid = blockIdx.x * 256 + threadIdx.x;
  int i = tid & 63;
  int rest = tid >> 6;
  int h = rest & ((1 << log2H) - 1);
  int token = rest >> log2H;
  float pos = (float)pos_ids[token];
  // freq = 500000^(-i/64); log2(500000) = 18.93156856932417
  float fr = __builtin_exp2f(-(float)i * (18.93156856932417f / 64.0f));
  float wl = 6.283185307179586f / fr;
  float f2;
  if (wl < 2048.0f) f2 = fr;
  else if (wl > 8192.0f) f2 = fr * 0.125f;
  else {
    float sm = (8192.0f / wl - 1.0f) * (1.0f / 3.0f);
    f2 = (1.0f - sm) * fr * 0.125f + sm * fr;
  }
  float ang = pos * f2;
  float ss = sinf(ang), cc = cosf(ang);
  size_t base = (size_t)token * row_stride + (size_t)h * 128 + i;
  float x1 = bf2f(X[base]), x2 = bf2f(X[base + 64]);
  X[base] = f2bf(x1 * cc - x2 * ss);
  X[base + 64] = f2bf(x2 * cc + x1 * ss);
}

// ---------------- causal GQA flash attention ----------------
// grid (16, 32, 4) = (qt rev, h, b), 256 threads. BM=BN=64; wave w owns Q rows [w*16,w*16+16).
// K staged in [key][d] layout, V^T staged in [d][key] layout, both via global_load_lds
// with XOR-swizzled 16B groups so all ds_read_b128 fragment reads are conflict-free.
__global__ __launch_bounds__(256) void attn_kernel(const u16* __restrict__ Qg,
                                                   const u16* __restrict__ Kg,
                                                   const u16* __restrict__ VTg,
                                                   u16* __restrict__ Og,
                                                   int QS, int KS) {
  const int qt = 15 - blockIdx.x;  // long blocks dispatch first (load balance)
  const int h = blockIdx.y, b = blockIdx.z;
  const int kvh = h >> 2;  // GQA group of 4
  const int t = threadIdx.x, lane = t & 63, w = t >> 6;
  const int col = lane & 15, quad = lane >> 4;

  __shared__ u16 Ks[64 * 128];   // 16 KB, swizzled: [key][ (g ^ (key&15))*8 + e ]
  __shared__ u16 Vt[128 * 64];   // 16 KB, swizzled: [d]  [ (g ^ (d&7))*8 + e ]
  __shared__ u16 Ps[4][16][72];  // per-wave P strip, 9 KB

  // ---- stage Q (into Ks buffer) and pull A-fragments into registers ----
  {
    const u16* Qbase = Qg + (size_t)(b * 1024 + qt * 64) * QS + h * 128;
#pragma unroll
    for (int c = 0; c < 4; c++) {
      int ch = w * 4 + c;
      int row = ch * 4 + (lane >> 4);
      int g = (lane & 15) ^ (row & 15);
      gl_lds16(Qbase + (size_t)row * QS + g * 8, Ks + ch * 512);
    }
  }
  __syncthreads();
  bf16x8 qa[4];
#pragma unroll
  for (int kk = 0; kk < 4; kk++) {
    int row = w * 16 + col;
    qa[kk] = *(const bf16x8*)&Ks[row * 128 + (((quad + 4 * kk) ^ col) << 3)];
  }

  f32x4 o[8] = {};
  float m_i[4] = {-3.0e38f, -3.0e38f, -3.0e38f, -3.0e38f};
  float l_i[4] = {};

  const float cf = 0.08838834764831845f * 1.4426950408889634f;  // scale * log2(e)
  const int qrow0 = qt * 64 + w * 16 + quad * 4;

  const u16* Kbase = Kg + (size_t)(b * 1024) * KS + kvh * 128;
  const u16* Vbase = VTg + (size_t)(kvh * 128) * 4096 + b * 1024;

  for (int j = 0; j <= qt; j++) {
    __syncthreads();  // everyone done reading previous tile (and Q regs at j=0)
#pragma unroll
    for (int c = 0; c < 4; c++) {
      int ch = w * 4 + c;
      // K chunk: 4 rows (keys) of 128B
      int krow = ch * 4 + (lane >> 4);
      int kg = (lane & 15) ^ (krow & 15);
      gl_lds16(Kbase + (size_t)(j * 64 + krow) * KS + kg * 8, Ks + ch * 512);
      // V^T chunk: 8 rows (d) of 64B segments
      int vrow = ch * 8 + (lane >> 3);
      int vg = (lane & 7) ^ (vrow & 7);
      gl_lds16(Vbase + (size_t)vrow * 4096 + j * 64 + vg * 8, Vt + ch * 512);
    }
    __syncthreads();  // drains vmcnt before barrier

    // S = Q K^T  (rows=q via A, cols=key via B)
    f32x4 s[4] = {};
#pragma unroll
    for (int nb = 0; nb < 4; nb++) {
      int key = nb * 16 + col;
#pragma unroll
      for (int kk = 0; kk < 4; kk++) {
        bf16x8 kb2 = *(const bf16x8*)&Ks[key * 128 + (((quad + 4 * kk) ^ col) << 3)];
        s[nb] = __builtin_amdgcn_mfma_f32_16x16x32_bf16(qa[kk], kb2, s[nb], 0, 0, 0);
      }
    }

    if (j == qt) {  // diagonal tile: causal mask
#pragma unroll
      for (int nb = 0; nb < 4; nb++)
#pragma unroll
        for (int rr = 0; rr < 4; rr++)
          if (j * 64 + nb * 16 + col > qrow0 + rr) s[nb][rr] = -3.0e38f;
    }

    // online softmax; rows live across the 16 lanes of each quad
    float mnew[4];
#pragma unroll
    for (int rr = 0; rr < 4; rr++) {
      mnew[rr] = m_i[rr];
#pragma unroll
      for (int nb = 0; nb < 4; nb++) mnew[rr] = fmaxf(mnew[rr], s[nb][rr]);
    }
#pragma unroll
    for (int off = 1; off < 16; off <<= 1)
#pragma unroll
      for (int rr = 0; rr < 4; rr++)
        mnew[rr] = fmaxf(mnew[rr], __shfl_xor(mnew[rr], off));

    float p[4][4], rs[4], alpha[4];
#pragma unroll
    for (int rr = 0; rr < 4; rr++) {
      alpha[rr] = __builtin_exp2f((m_i[rr] - mnew[rr]) * cf);
      m_i[rr] = mnew[rr];
      rs[rr] = 0.0f;
    }
#pragma unroll
    for (int nb = 0; nb < 4; nb++)
#pragma unroll
      for (int rr = 0; rr < 4; rr++) {
        p[nb][rr] = __builtin_exp2f((s[nb][rr] - mnew[rr]) * cf);
        rs[rr] += p[nb][rr];
      }
#pragma unroll
    for (int off = 1; off < 16; off <<= 1)
#pragma unroll
      for (int rr = 0; rr < 4; rr++) rs[rr] += __shfl_xor(rs[rr], off);
#pragma unroll
    for (int rr = 0; rr < 4; rr++) l_i[rr] = l_i[rr] * alpha[rr] + rs[rr];
#pragma unroll
    for (int nb2 = 0; nb2 < 8; nb2++)
#pragma unroll
      for (int rr = 0; rr < 4; rr++) o[nb2][rr] *= alpha[rr];

    // P: C-layout -> LDS -> A-layout (per-wave slice; same-wave LDS in-order)
#pragma unroll
    for (int nb = 0; nb < 4; nb++)
#pragma unroll
      for (int rr = 0; rr < 4; rr++)
        Ps[w][quad * 4 + rr][nb * 16 + col] = f2bf(p[nb][rr]);

    bf16x8 pa0 = *(const bf16x8*)&Ps[w][col][quad * 8];
    bf16x8 pa1 = *(const bf16x8*)&Ps[w][col][quad * 8 + 32];
#pragma unroll
    for (int nb2 = 0; nb2 < 8; nb2++) {
      int d = nb2 * 16 + col;
      bf16x8 vb0 = *(const bf16x8*)&Vt[d * 64 + ((quad ^ (col & 7)) << 3)];
      bf16x8 vb1 = *(const bf16x8*)&Vt[d * 64 + ((((quad + 4) & 7) ^ (col & 7)) << 3)];
      o[nb2] = __builtin_amdgcn_mfma_f32_16x16x32_bf16(pa0, vb0, o[nb2], 0, 0, 0);
      o[nb2] = __builtin_amdgcn_mfma_f32_16x16x32_bf16(pa1, vb1, o[nb2], 0, 0, 0);
    }
  }

  float inv[4];
#pragma unroll
  for (int rr = 0; rr < 4; rr++) inv[rr] = 1.0f / l_i[rr];
#pragma unroll
  for (int nb2 = 0; nb2 < 8; nb2++)
#pragma unroll
    for (int rr = 0; rr < 4; rr++) {
      size_t off2 = (size_t)(b * 1024 + qt * 64 + w * 16 + quad * 4 + rr) * 4096 +
                    h * 128 + nb2 * 16 + col;
      Og[off2] = f2bf(o[nb2][rr] * inv[rr]);
    }
}

extern "C" void kernel_launch(void* const* d_in, const int* in_sizes, int n_in,
                              void* d_out, int out_size, void* d_ws, size_t ws_size,
                              hipStream_t stream) {
  const float* hs = (const float*)d_in[0];
  const float* wq = (const float*)d_in[1];
  const float* wk = (const float*)d_in[2];
  const float* wv = (const float*)d_in[3];
  const float* wo = (const float*)d_in[4];
  const int* pos = (const int*)d_in[6];
  float* out = (float*)d_out;

  char* ws = (char*)d_ws;
  const size_t MB = 1ull << 20;
  // Phase 1 layout:
  u16* hs_bf   = (u16*)(ws + 0);        // 32 MB [4096][4096]
  u16* wqkv_bf = (u16*)(ws + 32 * MB);  // 48 MB [6144][4096] (wq|wk|wv stacked)
  u16* QKV     = (u16*)(ws + 80 * MB);  // 48 MB [4096 tok][6144]: Q|K|V
  // Phase 2 layout (after QKV GEMM, hs_bf & wqkv_bf dead):
  u16* wo_bf = (u16*)(ws + 0);          // 32 MB
  u16* AOb   = (u16*)(ws + 32 * MB);    // 32 MB [4096][4096] attention out
  u16* VTb   = (u16*)(ws + 64 * MB);    // 8 MB  [1024 d][4096 tok]

  // converts: hs + stacked QKV weight
  cvt_kernel<<<16384, 256, 0, stream>>>(hs, hs_bf, 4194304);
  cvt_kernel<<<16384, 256, 0, stream>>>(wq, wqkv_bf, 4194304);
  cvt_kernel<<<4096, 256, 0, stream>>>(wk, wqkv_bf + 16777216, 1048576);
  cvt_kernel<<<4096, 256, 0, stream>>>(wv, wqkv_bf + 20971520, 1048576);

  // fused QKV projection: [4096][6144], 256^2 tiles, grid 24x16 = 384 blocks
  gemm8p<1><<<dim3(24, 16), 512, 0, stream>>>(hs_bf, wqkv_bf, QKV, 4096, 6144, 4096);

  // RoPE on Q (cols 0..4095) and K (cols 4096..5119), in place, stride 6144
  rope_kernel<<<32768, 256, 0, stream>>>(QKV, pos, 5, 6144);
  rope_kernel<<<8192, 256, 0, stream>>>(QKV + 4096, pos, 3, 6144);

  // V^T: transpose QKV[:, 5120:6144] -> VTb [1024][4096]
  transpose_kernel<<<dim3(16, 64), 256, 0, stream>>>(QKV + 5120, VTb, 6144, 4096);

  // convert wo (into dead hs_bf slot)
  cvt_kernel<<<16384, 256, 0, stream>>>(wo, wo_bf, 4194304);

  // attention: Q stride 6144, K stride 6144, V^T [1024][4096]
  attn_kernel<<<dim3(16, 32, 4), 256, 0, stream>>>(QKV, QKV + 4096, VTb, AOb, 6144, 6144);

  // output projection -> fp32 d_out
  gemm8p<0><<<dim3(16, 16), 512, 0, stream>>>(AOb, wo_bf, out, 4096, 4096, 4096);
}

// Round 5
// 801.450 us; speedup vs baseline: 1.0164x; 1.0164x over previous
//
#include <hip/hip_runtime.h>

typedef unsigned short u16;
typedef __bf16 bf16x8 __attribute__((ext_vector_type(8)));
typedef float f32x4 __attribute__((ext_vector_type(4)));

__device__ __forceinline__ u16 f2bf(float f) {
  unsigned int u = __float_as_uint(f);
  u += 0x7fffu + ((u >> 16) & 1u);
  return (u16)(u >> 16);
}
__device__ __forceinline__ float bf2f(u16 v) {
  return __uint_as_float(((unsigned int)v) << 16);
}

// async global->LDS, 16B per lane. LDS dest must be wave-uniform base; HW adds lane*16.
__device__ __forceinline__ void gl_lds16(const u16* g, u16* l) {
  auto* lp = reinterpret_cast<__attribute__((address_space(3))) unsigned int*>(
      reinterpret_cast<uintptr_t>(l));
  auto* gp = reinterpret_cast<const __attribute__((address_space(1))) unsigned int*>(
      reinterpret_cast<uintptr_t>(g));
  __builtin_amdgcn_global_load_lds(gp, lp, 16, 0, 0);
}

// ---------------- fp32 -> bf16 convert ----------------
__global__ __launch_bounds__(256) void cvt_kernel(const float* __restrict__ in,
                                                  u16* __restrict__ out, int n4) {
  int i = blockIdx.x * 256 + threadIdx.x;
  if (i >= n4) return;
  float4 v = ((const float4*)in)[i];
  ushort4 o;
  o.x = f2bf(v.x); o.y = f2bf(v.y); o.z = f2bf(v.z); o.w = f2bf(v.w);
  ((ushort4*)out)[i] = o;
}

// ---------------- 256x256 8-phase bf16 GEMM, C[m][n] = sum_k A[m][k]*B[n][k] ----
// (round-3 measured-best configuration: BK=32, 64 KiB LDS, paired-row swizzle,
//  counted vmcnt(2), 0 bank conflicts, 233 us @ QKV)

#define BARRIER() __builtin_amdgcn_s_barrier()
#define VMCNT(n_) asm volatile("s_waitcnt vmcnt(" #n_ ")" ::: "memory")
#define PH_SYNC()                                           \
  do {                                                      \
    BARRIER();                                              \
    asm volatile("s_waitcnt lgkmcnt(0)" ::: "memory");      \
    __builtin_amdgcn_sched_barrier(0);                      \
  } while (0)

#define STAGE_A(b_, h_, kt_)                                                        \
  gl_lds16(gA + (size_t)((h_) * 128) * K + (size_t)(kt_) * 32,                      \
           lds + (b_) * 16384 + (h_) * 4096 + w * 512)

#define STAGE_B(b_, h_, kt_)                                                        \
  gl_lds16(gB + (size_t)((h_) * 128) * K + (size_t)(kt_) * 32,                      \
           lds + (b_) * 16384 + 8192 + (h_) * 4096 + w * 512)

#define LOADS_A(b_, qm_)                                                            \
  do {                                                                              \
    _Pragma("unroll") for (int i2 = 0; i2 < 4; i2++)                                \
      ar[i2] = *(const bf16x8*)&lds[(b_) * 16384 + arow + ((qm_)*4 + i2) * 512 + ax]; \
  } while (0)

#define LOADS_B(b_, qn_)                                                            \
  do {                                                                              \
    _Pragma("unroll") for (int j2 = 0; j2 < 2; j2++)                                \
      br[(qn_)*2 + j2] =                                                            \
          *(const bf16x8*)&lds[(b_) * 16384 + brow + ((qn_)*2 + j2) * 512 + ax];    \
  } while (0)

#define MFMA_Q(qm_, qn_)                                                            \
  do {                                                                              \
    __builtin_amdgcn_s_setprio(1);                                                  \
    _Pragma("unroll") for (int i2 = 0; i2 < 4; i2++) {                              \
      _Pragma("unroll") for (int j2 = 0; j2 < 2; j2++) {                            \
        acc[(qm_)*4 + i2][(qn_)*2 + j2] = __builtin_amdgcn_mfma_f32_16x16x32_bf16(  \
            ar[i2], br[(qn_)*2 + j2], acc[(qm_)*4 + i2][(qn_)*2 + j2], 0, 0, 0);    \
      }                                                                             \
    }                                                                               \
    __builtin_amdgcn_s_setprio(0);                                                  \
  } while (0)

template <int OUT_BF16>
__global__ __launch_bounds__(512, 2) void gemm8p(const u16* __restrict__ A,
                                                 const u16* __restrict__ B,
                                                 void* __restrict__ Cv,
                                                 int M, int N, int K) {
  __shared__ u16 lds[32768];  // 64 KiB: 2 bufs x (A 8192 + B 8192) u16
  (void)M;
  const int t = threadIdx.x, lane = t & 63, w = t >> 6;
  const int col = lane & 15, quad = lane >> 4;
  const int wm = w >> 2, wn = w & 3;  // 2x4 wave grid

  // bijective XCD-aware block remap (m204 variant)
  const int nwg = gridDim.x * gridDim.y;
  const int wgid = blockIdx.y * gridDim.x + blockIdx.x;
  const int xcd = wgid & 7, lin = wgid >> 3;
  const int q8 = nwg >> 3, r8 = nwg & 7;
  const int nid = (xcd < r8 ? xcd * (q8 + 1) : r8 * (q8 + 1) + (xcd - r8) * q8) + lin;
  const int m0 = (nid / gridDim.x) * 256;
  const int n0 = (nid % gridDim.x) * 256;

  // staging with paired-row swizzle: thread t writes LDS byte t*16 of the
  // half-tile, which is (pair = t>>3, slot s' = t&7). Unswizzled s = s'^(pair&7)
  // gives row = 2*pair + (s>>2), 16B k-unit = s&3.
  const int pr_ = t >> 3;
  const int s_ = (t & 7) ^ (pr_ & 7);
  const int srow = (pr_ << 1) | (s_ >> 2);
  const int sj = s_ & 3;
  const u16* gA = A + (size_t)(m0 + srow) * K + sj * 8;
  const u16* gB = B + (size_t)(n0 + srow) * K + sj * 8;

  // fragment-read bases (u16 units). For row = rbase + col (rbase mult of 16),
  // k-unit = quad: lds_u16 = rbase*32 + (col>>1)*64 + ((s^(col>>1))<<3),
  // s = 4*(col&1) + quad. Lane-constant part:
  const int arow = wm * 4096;
  const int brow = 8192 + wn * 2048;
  const int ax = (col >> 1) * 64 +
                 (((((col & 1) << 2) | quad) ^ (col >> 1)) << 3);

  f32x4 acc[8][4] = {};
  bf16x8 ar[4], br[4];  // br[0..1]=qn0, br[2..3]=qn1

  // prologue: tile0 -> buf0 (A,B), tile1.B -> buf1; wait tile0 (leave 2 in flight)
  STAGE_A(0, 0, 0); STAGE_A(0, 1, 0);
  STAGE_B(0, 0, 0); STAGE_B(0, 1, 0);
  STAGE_B(1, 0, 1); STAGE_B(1, 1, 1);
  VMCNT(2);
  BARRIER();

  const int NIT = K >> 6;  // 2 K-tiles (64 k) per iteration
  for (int it = 0; it < NIT - 1; ++it) {
    const int kt = it * 2;
    // P1: buf0 quadrant (0,0); stage buf1.Ah0 <- tile kt+1
    LOADS_A(0, 0); LOADS_B(0, 0);
    STAGE_A(1, 0, kt + 1);
    PH_SYNC(); MFMA_Q(0, 0); BARRIER();
    // P2: buf0 (0,1); stage buf1.Ah1
    LOADS_B(0, 1);
    STAGE_A(1, 1, kt + 1);
    PH_SYNC(); MFMA_Q(0, 1); BARRIER();
    // P3: buf0 (1,0); stage buf0.Bh0 <- tile kt+2
    LOADS_A(0, 1);
    STAGE_B(0, 0, kt + 2);
    PH_SYNC(); MFMA_Q(1, 0); BARRIER();
    // P4: buf0 (1,1); stage buf0.Bh1; ensure buf1 tile kt+1 resident
    STAGE_B(0, 1, kt + 2);
    PH_SYNC(); MFMA_Q(1, 1); VMCNT(2); BARRIER();
    // P5: buf1 (0,0); stage buf0.Ah0 <- tile kt+2
    LOADS_A(1, 0); LOADS_B(1, 0);
    STAGE_A(0, 0, kt + 2);
    PH_SYNC(); MFMA_Q(0, 0); BARRIER();
    // P6: buf1 (0,1); stage buf0.Ah1
    LOADS_B(1, 1);
    STAGE_A(0, 1, kt + 2);
    PH_SYNC(); MFMA_Q(0, 1); BARRIER();
    // P7: buf1 (1,0); stage buf1.Bh0 <- tile kt+3
    LOADS_A(1, 1);
    STAGE_B(1, 0, kt + 3);
    PH_SYNC(); MFMA_Q(1, 0); BARRIER();
    // P8: buf1 (1,1); stage buf1.Bh1; ensure buf0 tile kt+2 resident
    STAGE_B(1, 1, kt + 3);
    PH_SYNC(); MFMA_Q(1, 1); VMCNT(2); BARRIER();
  }

  // epilogue: tiles 2*NIT-2 (buf0, resident), 2*NIT-1 (buf1: B staged, stage A now)
  {
    const int kl = 2 * NIT - 1;
    LOADS_A(0, 0); LOADS_B(0, 0);
    STAGE_A(1, 0, kl);
    PH_SYNC(); MFMA_Q(0, 0); BARRIER();
    LOADS_B(0, 1);
    STAGE_A(1, 1, kl);
    PH_SYNC(); MFMA_Q(0, 1); BARRIER();
    LOADS_A(0, 1);
    PH_SYNC(); MFMA_Q(1, 0); BARRIER();
    PH_SYNC(); MFMA_Q(1, 1); VMCNT(0); BARRIER();
    LOADS_A(1, 0); LOADS_B(1, 0);
    PH_SYNC(); MFMA_Q(0, 0); BARRIER();
    LOADS_B(1, 1);
    PH_SYNC(); MFMA_Q(0, 1); BARRIER();
    LOADS_A(1, 1);
    PH_SYNC(); MFMA_Q(1, 0); BARRIER();
    MFMA_Q(1, 1);
  }

  // C write: col = lane&15 (n side), row = quad*4 + reg (m side)
#pragma unroll
  for (int i = 0; i < 8; i++) {
#pragma unroll
    for (int j = 0; j < 4; j++) {
      const int mb = m0 + wm * 128 + i * 16 + quad * 4;
      const int n = n0 + wn * 64 + j * 16 + col;
#pragma unroll
      for (int r = 0; r < 4; r++) {
        float v = acc[i][j][r];
        if constexpr (OUT_BF16)
          ((u16*)Cv)[(size_t)(mb + r) * N + n] = f2bf(v);
        else
          ((float*)Cv)[(size_t)(mb + r) * N + n] = v;
      }
    }
  }
}

// ---------------- 64x64-tiled u16 transpose: out[c][r] = in[r][c] ----------------
__global__ __launch_bounds__(256) void transpose_kernel(const u16* __restrict__ in,
                                                        u16* __restrict__ out,
                                                        int in_stride, int out_stride) {
  __shared__ u16 tile[64][72];
  const int t = threadIdx.x;
  const int bm = blockIdx.y;  // input row tile
  const int bn = blockIdx.x;  // input col tile
  const int r = t >> 3, c = (t & 7) * 8;
  const u16* src = in + (size_t)(bm * 64 + r) * in_stride + bn * 64 + c;
  *(uint4*)&tile[r][c] = *(const uint4*)src;
  *(uint4*)&tile[r + 32][c] = *(const uint4*)(src + (size_t)32 * in_stride);
  __syncthreads();
  u16 vals[8];
  u16* dst = out + (size_t)(bn * 64 + r) * out_stride + bm * 64 + c;
#pragma unroll
  for (int i = 0; i < 8; i++) vals[i] = tile[c + i][r];
  *(uint4*)dst = *(uint4*)vals;
#pragma unroll
  for (int i = 0; i < 8; i++) vals[i] = tile[c + i][r + 32];
  *(uint4*)(dst + (size_t)32 * out_stride) = *(uint4*)vals;
}

// ---------------- Llama-3.1 RoPE (rotate-half, non-interleaved) ----------------
__global__ __launch_bounds__(256) void rope_kernel(u16* __restrict__ X,
                                                   const int* __restrict__ pos_ids,
                                                   int log2H, int row_stride) {
  int tid = blockIdx.x * 256 + threadIdx.x;
  int i = tid & 63;
  int rest = tid >> 6;
  int h = rest & ((1 << log2H) - 1);
  int token = rest >> log2H;
  float pos = (float)pos_ids[token];
  // freq = 500000^(-i/64); log2(500000) = 18.93156856932417
  float fr = __builtin_exp2f(-(float)i * (18.93156856932417f / 64.0f));
  float wl = 6.283185307179586f / fr;
  float f2;
  if (wl < 2048.0f) f2 = fr;
  else if (wl > 8192.0f) f2 = fr * 0.125f;
  else {
    float sm = (8192.0f / wl - 1.0f) * (1.0f / 3.0f);
    f2 = (1.0f - sm) * fr * 0.125f + sm * fr;
  }
  float ang = pos * f2;
  float ss = sinf(ang), cc = cosf(ang);
  size_t base = (size_t)token * row_stride + (size_t)h * 128 + i;
  float x1 = bf2f(X[base]), x2 = bf2f(X[base + 64]);
  X[base] = f2bf(x1 * cc - x2 * ss);
  X[base + 64] = f2bf(x2 * cc + x1 * ss);
}

// ---------------- causal GQA flash attention ----------------
// grid (16, 32, 4) = (qt rev, h, b), 256 threads. BM=BN=64; wave w owns Q rows [w*16,w*16+16).
// K staged in [key][d] layout, V^T staged in [d][key] layout via global_load_lds,
// XOR-swizzled 16B groups -> conflict-free ds_read_b128 fragment reads.
// NEW: double-buffered K/V pipeline. Tile j+1's global_load_lds issues at the top
// of iteration j; counted vmcnt(8) (= exactly this wave's 8 loads for tile j)
// + raw s_barrier replaces the draining __syncthreads, so tile j+1's HBM/L2
// latency hides under iteration j's full compute. Never vmcnt(0) until last tile.
__global__ __launch_bounds__(256) void attn_kernel(const u16* __restrict__ Qg,
                                                   const u16* __restrict__ Kg,
                                                   const u16* __restrict__ VTg,
                                                   u16* __restrict__ Og,
                                                   int QS, int KS) {
  const int qt = 15 - blockIdx.x;  // long blocks dispatch first (load balance)
  const int h = blockIdx.y, b = blockIdx.z;
  const int kvh = h >> 2;  // GQA group of 4
  const int t = threadIdx.x, lane = t & 63, w = t >> 6;
  const int col = lane & 15, quad = lane >> 4;

  __shared__ u16 Ks[2][64 * 128];  // 32 KB, swizzled [key][ (g ^ (key&15))*8 + e ]
  __shared__ u16 Vt[2][128 * 64];  // 32 KB, swizzled [d][ (g ^ (d&7))*8 + e ]
  __shared__ u16 Ps[4][16][72];    // per-wave P strip, 9 KB

  const u16* Kbase = Kg + (size_t)(b * 1024) * KS + kvh * 128;
  const u16* Vbase = VTg + (size_t)(kvh * 128) * 4096 + b * 1024;

  // stage tile j of K/V into buffer bb (8 gl_lds16 per wave)
  auto stage_kv = [&](int bb, int j) {
#pragma unroll
    for (int c = 0; c < 4; c++) {
      int ch = w * 4 + c;
      int krow = ch * 4 + (lane >> 4);
      int kg = (lane & 15) ^ (krow & 15);
      gl_lds16(Kbase + (size_t)(j * 64 + krow) * KS + kg * 8, &Ks[bb][ch * 512]);
      int vrow = ch * 8 + (lane >> 3);
      int vg = (lane & 7) ^ (vrow & 7);
      gl_lds16(Vbase + (size_t)vrow * 4096 + j * 64 + vg * 8, &Vt[bb][ch * 512]);
    }
  };

  // ---- stage Q (into Ks[0]) and tile0 (into buf1, overlapped) ----
  {
    const u16* Qbase = Qg + (size_t)(b * 1024 + qt * 64) * QS + h * 128;
#pragma unroll
    for (int c = 0; c < 4; c++) {
      int ch = w * 4 + c;
      int row = ch * 4 + (lane >> 4);
      int g = (lane & 15) ^ (row & 15);
      gl_lds16(Qbase + (size_t)row * QS + g * 8, &Ks[0][ch * 512]);
    }
  }
  stage_kv(1, 0);  // tile0 -> buf1; overlaps the Q wait
  __syncthreads();
  bf16x8 qa[4];
#pragma unroll
  for (int kk = 0; kk < 4; kk++) {
    int row = w * 16 + col;
    qa[kk] = *(const bf16x8*)&Ks[0][row * 128 + (((quad + 4 * kk) ^ col) << 3)];
  }
  BARRIER();  // all waves read Q -> Ks[0] free for tile1

  f32x4 o[8] = {};
  float m_i[4] = {-3.0e38f, -3.0e38f, -3.0e38f, -3.0e38f};
  float l_i[4] = {};

  const float cf = 0.08838834764831845f * 1.4426950408889634f;  // scale * log2(e)
  const int qrow0 = qt * 64 + w * 16 + quad * 4;

  for (int j = 0; j <= qt; j++) {
    const int bb = (j + 1) & 1;  // buffer holding tile j (tile0 -> buf1)
    if (j < qt) {
      stage_kv(bb ^ 1, j + 1);  // issue next tile; overlaps this tile's compute
      VMCNT(8);                 // tile j's 8 loads (oldest) complete
    } else {
      VMCNT(0);
    }
    BARRIER();  // all waves' tile-j stages landed

    const u16* Ksb = &Ks[bb][0];
    const u16* Vtb = &Vt[bb][0];

    // S = Q K^T  (rows=q via A, cols=key via B)
    f32x4 s[4] = {};
    __builtin_amdgcn_s_setprio(1);
#pragma unroll
    for (int nb = 0; nb < 4; nb++) {
      int key = nb * 16 + col;
#pragma unroll
      for (int kk = 0; kk < 4; kk++) {
        bf16x8 kb2 = *(const bf16x8*)&Ksb[key * 128 + (((quad + 4 * kk) ^ col) << 3)];
        s[nb] = __builtin_amdgcn_mfma_f32_16x16x32_bf16(qa[kk], kb2, s[nb], 0, 0, 0);
      }
    }
    __builtin_amdgcn_s_setprio(0);

    if (j == qt) {  // diagonal tile: causal mask
#pragma unroll
      for (int nb = 0; nb < 4; nb++)
#pragma unroll
        for (int rr = 0; rr < 4; rr++)
          if (j * 64 + nb * 16 + col > qrow0 + rr) s[nb][rr] = -3.0e38f;
    }

    // online softmax; rows live across the 16 lanes of each quad
    float mnew[4];
#pragma unroll
    for (int rr = 0; rr < 4; rr++) {
      mnew[rr] = m_i[rr];
#pragma unroll
      for (int nb = 0; nb < 4; nb++) mnew[rr] = fmaxf(mnew[rr], s[nb][rr]);
    }
#pragma unroll
    for (int off = 1; off < 16; off <<= 1)
#pragma unroll
      for (int rr = 0; rr < 4; rr++)
        mnew[rr] = fmaxf(mnew[rr], __shfl_xor(mnew[rr], off));

    float p[4][4], rs[4], alpha[4];
#pragma unroll
    for (int rr = 0; rr < 4; rr++) {
      alpha[rr] = __builtin_exp2f((m_i[rr] - mnew[rr]) * cf);
      m_i[rr] = mnew[rr];
      rs[rr] = 0.0f;
    }
#pragma unroll
    for (int nb = 0; nb < 4; nb++)
#pragma unroll
      for (int rr = 0; rr < 4; rr++) {
        p[nb][rr] = __builtin_exp2f((s[nb][rr] - mnew[rr]) * cf);
        rs[rr] += p[nb][rr];
      }
#pragma unroll
    for (int off = 1; off < 16; off <<= 1)
#pragma unroll
      for (int rr = 0; rr < 4; rr++) rs[rr] += __shfl_xor(rs[rr], off);
#pragma unroll
    for (int rr = 0; rr < 4; rr++) l_i[rr] = l_i[rr] * alpha[rr] + rs[rr];
#pragma unroll
    for (int nb2 = 0; nb2 < 8; nb2++)
#pragma unroll
      for (int rr = 0; rr < 4; rr++) o[nb2][rr] *= alpha[rr];

    // P: C-layout -> LDS -> A-layout (per-wave slice; same-wave LDS in-order)
#pragma unroll
    for (int nb = 0; nb < 4; nb++)
#pragma unroll
      for (int rr = 0; rr < 4; rr++)
        Ps[w][quad * 4 + rr][nb * 16 + col] = f2bf(p[nb][rr]);

    bf16x8 pa0 = *(const bf16x8*)&Ps[w][col][quad * 8];
    bf16x8 pa1 = *(const bf16x8*)&Ps[w][col][quad * 8 + 32];
    __builtin_amdgcn_s_setprio(1);
#pragma unroll
    for (int nb2 = 0; nb2 < 8; nb2++) {
      int d = nb2 * 16 + col;
      bf16x8 vb0 = *(const bf16x8*)&Vtb[d * 64 + ((quad ^ (col & 7)) << 3)];
      bf16x8 vb1 = *(const bf16x8*)&Vtb[d * 64 + ((((quad + 4) & 7) ^ (col & 7)) << 3)];
      o[nb2] = __builtin_amdgcn_mfma_f32_16x16x32_bf16(pa0, vb0, o[nb2], 0, 0, 0);
      o[nb2] = __builtin_amdgcn_mfma_f32_16x16x32_bf16(pa1, vb1, o[nb2], 0, 0, 0);
    }
    __builtin_amdgcn_s_setprio(0);

    BARRIER();  // all waves done reading buf bb before it's restaged
  }

  float inv[4];
#pragma unroll
  for (int rr = 0; rr < 4; rr++) inv[rr] = 1.0f / l_i[rr];
#pragma unroll
  for (int nb2 = 0; nb2 < 8; nb2++)
#pragma unroll
    for (int rr = 0; rr < 4; rr++) {
      size_t off2 = (size_t)(b * 1024 + qt * 64 + w * 16 + quad * 4 + rr) * 4096 +
                    h * 128 + nb2 * 16 + col;
      Og[off2] = f2bf(o[nb2][rr] * inv[rr]);
    }
}

extern "C" void kernel_launch(void* const* d_in, const int* in_sizes, int n_in,
                              void* d_out, int out_size, void* d_ws, size_t ws_size,
                              hipStream_t stream) {
  const float* hs = (const float*)d_in[0];
  const float* wq = (const float*)d_in[1];
  const float* wk = (const float*)d_in[2];
  const float* wv = (const float*)d_in[3];
  const float* wo = (const float*)d_in[4];
  const int* pos = (const int*)d_in[6];
  float* out = (float*)d_out;

  char* ws = (char*)d_ws;
  const size_t MB = 1ull << 20;
  // Phase 1 layout:
  u16* hs_bf   = (u16*)(ws + 0);        // 32 MB [4096][4096]
  u16* wqkv_bf = (u16*)(ws + 32 * MB);  // 48 MB [6144][4096] (wq|wk|wv stacked)
  u16* QKV     = (u16*)(ws + 80 * MB);  // 48 MB [4096 tok][6144]: Q|K|V
  // Phase 2 layout (after QKV GEMM, hs_bf & wqkv_bf dead):
  u16* wo_bf = (u16*)(ws + 0);          // 32 MB
  u16* AOb   = (u16*)(ws + 32 * MB);    // 32 MB [4096][4096] attention out
  u16* VTb   = (u16*)(ws + 64 * MB);    // 8 MB  [1024 d][4096 tok]

  // converts: hs + stacked QKV weight
  cvt_kernel<<<16384, 256, 0, stream>>>(hs, hs_bf, 4194304);
  cvt_kernel<<<16384, 256, 0, stream>>>(wq, wqkv_bf, 4194304);
  cvt_kernel<<<4096, 256, 0, stream>>>(wk, wqkv_bf + 16777216, 1048576);
  cvt_kernel<<<4096, 256, 0, stream>>>(wv, wqkv_bf + 20971520, 1048576);

  // fused QKV projection: [4096][6144], 256^2 tiles, grid 24x16 = 384 blocks
  gemm8p<1><<<dim3(24, 16), 512, 0, stream>>>(hs_bf, wqkv_bf, QKV, 4096, 6144, 4096);

  // RoPE on Q (cols 0..4095) and K (cols 4096..5119), in place, stride 6144
  rope_kernel<<<32768, 256, 0, stream>>>(QKV, pos, 5, 6144);
  rope_kernel<<<8192, 256, 0, stream>>>(QKV + 4096, pos, 3, 6144);

  // V^T: transpose QKV[:, 5120:6144] -> VTb [1024][4096]
  transpose_kernel<<<dim3(16, 64), 256, 0, stream>>>(QKV + 5120, VTb, 6144, 4096);

  // convert wo (into dead hs_bf slot)
  cvt_kernel<<<16384, 256, 0, stream>>>(wo, wo_bf, 4194304);

  // attention: Q stride 6144, K stride 6144, V^T [1024][4096]
  attn_kernel<<<dim3(16, 32, 4), 256, 0, stream>>>(QKV, QKV + 4096, VTb, AOb, 6144, 6144);

  // output projection -> fp32 d_out
  gemm8p<0><<<dim3(16, 16), 512, 0, stream>>>(AOb, wo_bf, out, 4096, 4096, 4096);
}

// Round 6
// 784.647 us; speedup vs baseline: 1.0382x; 1.0214x over previous
//
#include <hip/hip_runtime.h>

typedef unsigned short u16;
typedef __bf16 bf16x8 __attribute__((ext_vector_type(8)));
typedef float f32x4 __attribute__((ext_vector_type(4)));

__device__ __forceinline__ u16 f2bf(float f) {
  unsigned int u = __float_as_uint(f);
  u += 0x7fffu + ((u >> 16) & 1u);
  return (u16)(u >> 16);
}
__device__ __forceinline__ float bf2f(u16 v) {
  return __uint_as_float(((unsigned int)v) << 16);
}

// async global->LDS, 16B per lane. LDS dest must be wave-uniform base; HW adds lane*16.
__device__ __forceinline__ void gl_lds16(const u16* g, u16* l) {
  auto* lp = reinterpret_cast<__attribute__((address_space(3))) unsigned int*>(
      reinterpret_cast<uintptr_t>(l));
  auto* gp = reinterpret_cast<const __attribute__((address_space(1))) unsigned int*>(
      reinterpret_cast<uintptr_t>(g));
  __builtin_amdgcn_global_load_lds(gp, lp, 16, 0, 0);
}

// ---------------- fp32 -> bf16 convert ----------------
__global__ __launch_bounds__(256) void cvt_kernel(const float* __restrict__ in,
                                                  u16* __restrict__ out, int n4) {
  int i = blockIdx.x * 256 + threadIdx.x;
  if (i >= n4) return;
  float4 v = ((const float4*)in)[i];
  ushort4 o;
  o.x = f2bf(v.x); o.y = f2bf(v.y); o.z = f2bf(v.z); o.w = f2bf(v.w);
  ((ushort4*)out)[i] = o;
}

// ---------------- 256x256 8-phase bf16 GEMM, C[m][n] = sum_k A[m][k]*B[n][k] ----
// (round-3 measured-best configuration: BK=32, 64 KiB LDS, paired-row swizzle,
//  counted vmcnt(2), 0 bank conflicts, 230 us @ QKV)

#define BARRIER() __builtin_amdgcn_s_barrier()
#define VMCNT(n_) asm volatile("s_waitcnt vmcnt(" #n_ ")" ::: "memory")
#define PH_SYNC()                                           \
  do {                                                      \
    BARRIER();                                              \
    asm volatile("s_waitcnt lgkmcnt(0)" ::: "memory");      \
    __builtin_amdgcn_sched_barrier(0);                      \
  } while (0)

#define STAGE_A(b_, h_, kt_)                                                        \
  gl_lds16(gA + (size_t)((h_) * 128) * K + (size_t)(kt_) * 32,                      \
           lds + (b_) * 16384 + (h_) * 4096 + w * 512)

#define STAGE_B(b_, h_, kt_)                                                        \
  gl_lds16(gB + (size_t)((h_) * 128) * K + (size_t)(kt_) * 32,                      \
           lds + (b_) * 16384 + 8192 + (h_) * 4096 + w * 512)

#define LOADS_A(b_, qm_)                                                            \
  do {                                                                              \
    _Pragma("unroll") for (int i2 = 0; i2 < 4; i2++)                                \
      ar[i2] = *(const bf16x8*)&lds[(b_) * 16384 + arow + ((qm_)*4 + i2) * 512 + ax]; \
  } while (0)

#define LOADS_B(b_, qn_)                                                            \
  do {                                                                              \
    _Pragma("unroll") for (int j2 = 0; j2 < 2; j2++)                                \
      br[(qn_)*2 + j2] =                                                            \
          *(const bf16x8*)&lds[(b_) * 16384 + brow + ((qn_)*2 + j2) * 512 + ax];    \
  } while (0)

#define MFMA_Q(qm_, qn_)                                                            \
  do {                                                                              \
    __builtin_amdgcn_s_setprio(1);                                                  \
    _Pragma("unroll") for (int i2 = 0; i2 < 4; i2++) {                              \
      _Pragma("unroll") for (int j2 = 0; j2 < 2; j2++) {                            \
        acc[(qm_)*4 + i2][(qn_)*2 + j2] = __builtin_amdgcn_mfma_f32_16x16x32_bf16(  \
            ar[i2], br[(qn_)*2 + j2], acc[(qm_)*4 + i2][(qn_)*2 + j2], 0, 0, 0);    \
      }                                                                             \
    }                                                                               \
    __builtin_amdgcn_s_setprio(0);                                                  \
  } while (0)

template <int OUT_BF16>
__global__ __launch_bounds__(512, 2) void gemm8p(const u16* __restrict__ A,
                                                 const u16* __restrict__ B,
                                                 void* __restrict__ Cv,
                                                 int M, int N, int K) {
  __shared__ u16 lds[32768];  // 64 KiB: 2 bufs x (A 8192 + B 8192) u16
  (void)M;
  const int t = threadIdx.x, lane = t & 63, w = t >> 6;
  const int col = lane & 15, quad = lane >> 4;
  const int wm = w >> 2, wn = w & 3;  // 2x4 wave grid

  // bijective XCD-aware block remap (m204 variant)
  const int nwg = gridDim.x * gridDim.y;
  const int wgid = blockIdx.y * gridDim.x + blockIdx.x;
  const int xcd = wgid & 7, lin = wgid >> 3;
  const int q8 = nwg >> 3, r8 = nwg & 7;
  const int nid = (xcd < r8 ? xcd * (q8 + 1) : r8 * (q8 + 1) + (xcd - r8) * q8) + lin;
  const int m0 = (nid / gridDim.x) * 256;
  const int n0 = (nid % gridDim.x) * 256;

  // staging with paired-row swizzle: thread t writes LDS byte t*16 of the
  // half-tile, which is (pair = t>>3, slot s' = t&7). Unswizzled s = s'^(pair&7)
  // gives row = 2*pair + (s>>2), 16B k-unit = s&3.
  const int pr_ = t >> 3;
  const int s_ = (t & 7) ^ (pr_ & 7);
  const int srow = (pr_ << 1) | (s_ >> 2);
  const int sj = s_ & 3;
  const u16* gA = A + (size_t)(m0 + srow) * K + sj * 8;
  const u16* gB = B + (size_t)(n0 + srow) * K + sj * 8;

  // fragment-read bases (u16 units). For row = rbase + col (rbase mult of 16),
  // k-unit = quad: lds_u16 = rbase*32 + (col>>1)*64 + ((s^(col>>1))<<3),
  // s = 4*(col&1) + quad. Lane-constant part:
  const int arow = wm * 4096;
  const int brow = 8192 + wn * 2048;
  const int ax = (col >> 1) * 64 +
                 (((((col & 1) << 2) | quad) ^ (col >> 1)) << 3);

  f32x4 acc[8][4] = {};
  bf16x8 ar[4], br[4];  // br[0..1]=qn0, br[2..3]=qn1

  // prologue: tile0 -> buf0 (A,B), tile1.B -> buf1; wait tile0 (leave 2 in flight)
  STAGE_A(0, 0, 0); STAGE_A(0, 1, 0);
  STAGE_B(0, 0, 0); STAGE_B(0, 1, 0);
  STAGE_B(1, 0, 1); STAGE_B(1, 1, 1);
  VMCNT(2);
  BARRIER();

  const int NIT = K >> 6;  // 2 K-tiles (64 k) per iteration
  for (int it = 0; it < NIT - 1; ++it) {
    const int kt = it * 2;
    // P1: buf0 quadrant (0,0); stage buf1.Ah0 <- tile kt+1
    LOADS_A(0, 0); LOADS_B(0, 0);
    STAGE_A(1, 0, kt + 1);
    PH_SYNC(); MFMA_Q(0, 0); BARRIER();
    // P2: buf0 (0,1); stage buf1.Ah1
    LOADS_B(0, 1);
    STAGE_A(1, 1, kt + 1);
    PH_SYNC(); MFMA_Q(0, 1); BARRIER();
    // P3: buf0 (1,0); stage buf0.Bh0 <- tile kt+2
    LOADS_A(0, 1);
    STAGE_B(0, 0, kt + 2);
    PH_SYNC(); MFMA_Q(1, 0); BARRIER();
    // P4: buf0 (1,1); stage buf0.Bh1; ensure buf1 tile kt+1 resident
    STAGE_B(0, 1, kt + 2);
    PH_SYNC(); MFMA_Q(1, 1); VMCNT(2); BARRIER();
    // P5: buf1 (0,0); stage buf0.Ah0 <- tile kt+2
    LOADS_A(1, 0); LOADS_B(1, 0);
    STAGE_A(0, 0, kt + 2);
    PH_SYNC(); MFMA_Q(0, 0); BARRIER();
    // P6: buf1 (0,1); stage buf0.Ah1
    LOADS_B(1, 1);
    STAGE_A(0, 1, kt + 2);
    PH_SYNC(); MFMA_Q(0, 1); BARRIER();
    // P7: buf1 (1,0); stage buf1.Bh0 <- tile kt+3
    LOADS_A(1, 1);
    STAGE_B(1, 0, kt + 3);
    PH_SYNC(); MFMA_Q(1, 0); BARRIER();
    // P8: buf1 (1,1); stage buf1.Bh1; ensure buf0 tile kt+2 resident
    STAGE_B(1, 1, kt + 3);
    PH_SYNC(); MFMA_Q(1, 1); VMCNT(2); BARRIER();
  }

  // epilogue: tiles 2*NIT-2 (buf0, resident), 2*NIT-1 (buf1: B staged, stage A now)
  {
    const int kl = 2 * NIT - 1;
    LOADS_A(0, 0); LOADS_B(0, 0);
    STAGE_A(1, 0, kl);
    PH_SYNC(); MFMA_Q(0, 0); BARRIER();
    LOADS_B(0, 1);
    STAGE_A(1, 1, kl);
    PH_SYNC(); MFMA_Q(0, 1); BARRIER();
    LOADS_A(0, 1);
    PH_SYNC(); MFMA_Q(1, 0); BARRIER();
    PH_SYNC(); MFMA_Q(1, 1); VMCNT(0); BARRIER();
    LOADS_A(1, 0); LOADS_B(1, 0);
    PH_SYNC(); MFMA_Q(0, 0); BARRIER();
    LOADS_B(1, 1);
    PH_SYNC(); MFMA_Q(0, 1); BARRIER();
    LOADS_A(1, 1);
    PH_SYNC(); MFMA_Q(1, 0); BARRIER();
    MFMA_Q(1, 1);
  }

  // C write: col = lane&15 (n side), row = quad*4 + reg (m side)
#pragma unroll
  for (int i = 0; i < 8; i++) {
#pragma unroll
    for (int j = 0; j < 4; j++) {
      const int mb = m0 + wm * 128 + i * 16 + quad * 4;
      const int n = n0 + wn * 64 + j * 16 + col;
#pragma unroll
      for (int r = 0; r < 4; r++) {
        float v = acc[i][j][r];
        if constexpr (OUT_BF16)
          ((u16*)Cv)[(size_t)(mb + r) * N + n] = f2bf(v);
        else
          ((float*)Cv)[(size_t)(mb + r) * N + n] = v;
      }
    }
  }
}

// ---------------- 64x64-tiled u16 transpose: out[c][r] = in[r][c] ----------------
__global__ __launch_bounds__(256) void transpose_kernel(const u16* __restrict__ in,
                                                        u16* __restrict__ out,
                                                        int in_stride, int out_stride) {
  __shared__ u16 tile[64][72];
  const int t = threadIdx.x;
  const int bm = blockIdx.y;  // input row tile
  const int bn = blockIdx.x;  // input col tile
  const int r = t >> 3, c = (t & 7) * 8;
  const u16* src = in + (size_t)(bm * 64 + r) * in_stride + bn * 64 + c;
  *(uint4*)&tile[r][c] = *(const uint4*)src;
  *(uint4*)&tile[r + 32][c] = *(const uint4*)(src + (size_t)32 * in_stride);
  __syncthreads();
  u16 vals[8];
  u16* dst = out + (size_t)(bn * 64 + r) * out_stride + bm * 64 + c;
#pragma unroll
  for (int i = 0; i < 8; i++) vals[i] = tile[c + i][r];
  *(uint4*)dst = *(uint4*)vals;
#pragma unroll
  for (int i = 0; i < 8; i++) vals[i] = tile[c + i][r + 32];
  *(uint4*)(dst + (size_t)32 * out_stride) = *(uint4*)vals;
}

// ---------------- Llama-3.1 RoPE (rotate-half, non-interleaved) ----------------
__global__ __launch_bounds__(256) void rope_kernel(u16* __restrict__ X,
                                                   const int* __restrict__ pos_ids,
                                                   int log2H, int row_stride) {
  int tid = blockIdx.x * 256 + threadIdx.x;
  int i = tid & 63;
  int rest = tid >> 6;
  int h = rest & ((1 << log2H) - 1);
  int token = rest >> log2H;
  float pos = (float)pos_ids[token];
  // freq = 500000^(-i/64); log2(500000) = 18.93156856932417
  float fr = __builtin_exp2f(-(float)i * (18.93156856932417f / 64.0f));
  float wl = 6.283185307179586f / fr;
  float f2;
  if (wl < 2048.0f) f2 = fr;
  else if (wl > 8192.0f) f2 = fr * 0.125f;
  else {
    float sm = (8192.0f / wl - 1.0f) * (1.0f / 3.0f);
    f2 = (1.0f - sm) * fr * 0.125f + sm * fr;
  }
  float ang = pos * f2;
  float ss = sinf(ang), cc = cosf(ang);
  size_t base = (size_t)token * row_stride + (size_t)h * 128 + i;
  float x1 = bf2f(X[base]), x2 = bf2f(X[base + 64]);
  X[base] = f2bf(x1 * cc - x2 * ss);
  X[base + 64] = f2bf(x2 * cc + x1 * ss);
}

// ---------------- causal GQA flash attention, QBLK=128 ----------------
// grid (8, 32, 4) = (q-pair rev, h, b), 256 threads. Each block owns TWO 64-row
// q-tiles (qA=2*pair, qB=qA+1) of the same head, sharing all K/V staging:
// per staged 64-key tile the QK->softmax->PV body runs twice (tile A, tile B),
// halving barriers/vmcnt/stage cost per unit work and doubling MFMA density.
// Double-buffered K/V (counted vmcnt(8), never 0 until last tile). Causal mask
// is branch-free: key > qrow is self-gating for j < qX.
__global__ __launch_bounds__(256, 2) void attn_kernel(const u16* __restrict__ Qg,
                                                      const u16* __restrict__ Kg,
                                                      const u16* __restrict__ VTg,
                                                      u16* __restrict__ Og,
                                                      int QS, int KS) {
  const int qtp = 7 - blockIdx.x;  // pair index, long blocks dispatch first
  const int qA = qtp * 2, qB = qA + 1;
  const int h = blockIdx.y, b = blockIdx.z;
  const int kvh = h >> 2;  // GQA group of 4
  const int t = threadIdx.x, lane = t & 63, w = t >> 6;
  const int col = lane & 15, quad = lane >> 4;

  __shared__ u16 Ks[2][64 * 128];  // 32 KB, swizzled [key][ (g ^ (key&15))*8 + e ]
  __shared__ u16 Vt[2][128 * 64];  // 32 KB, swizzled [d][ (g ^ (d&7))*8 + e ]
  __shared__ u16 Ps[4][16][72];    // per-wave P strip, 9 KB

  const u16* Kbase = Kg + (size_t)(b * 1024) * KS + kvh * 128;
  const u16* Vbase = VTg + (size_t)(kvh * 128) * 4096 + b * 1024;

  // stage tile j of K/V into buffer bb (8 gl_lds16 per wave)
  auto stage_kv = [&](int bb, int j) {
#pragma unroll
    for (int c = 0; c < 4; c++) {
      int ch = w * 4 + c;
      int krow = ch * 4 + (lane >> 4);
      int kg = (lane & 15) ^ (krow & 15);
      gl_lds16(Kbase + (size_t)(j * 64 + krow) * KS + kg * 8, &Ks[bb][ch * 512]);
      int vrow = ch * 8 + (lane >> 3);
      int vg = (lane & 7) ^ (vrow & 7);
      gl_lds16(Vbase + (size_t)vrow * 4096 + j * 64 + vg * 8, &Vt[bb][ch * 512]);
    }
  };

  // ---- stage Q_A -> Ks[0], Q_B -> Vt[0], and KV tile0 -> buf1 (all overlap) ----
  {
    const u16* QbA = Qg + (size_t)(b * 1024 + qA * 64) * QS + h * 128;
    const u16* QbB = Qg + (size_t)(b * 1024 + qB * 64) * QS + h * 128;
#pragma unroll
    for (int c = 0; c < 4; c++) {
      int ch = w * 4 + c;
      int row = ch * 4 + (lane >> 4);
      int g = (lane & 15) ^ (row & 15);
      gl_lds16(QbA + (size_t)row * QS + g * 8, &Ks[0][ch * 512]);
      gl_lds16(QbB + (size_t)row * QS + g * 8, &Vt[0][ch * 512]);
    }
  }
  stage_kv(1, 0);  // KV tile0 -> buf1
  __syncthreads();  // drains all staging
  bf16x8 qaA[4], qaB[4];
#pragma unroll
  for (int kk = 0; kk < 4; kk++) {
    int row = w * 16 + col;
    int off = row * 128 + (((quad + 4 * kk) ^ col) << 3);
    qaA[kk] = *(const bf16x8*)&Ks[0][off];
    qaB[kk] = *(const bf16x8*)&Vt[0][off];
  }
  BARRIER();  // all waves read Q -> buf0 free

  f32x4 oA[8] = {}, oB[8] = {};
  float mA[4] = {-3.0e38f, -3.0e38f, -3.0e38f, -3.0e38f};
  float mB[4] = {-3.0e38f, -3.0e38f, -3.0e38f, -3.0e38f};
  float lA[4] = {}, lB[4] = {};

  const float cf = 0.08838834764831845f * 1.4426950408889634f;  // scale * log2(e)
  const int qr0A = qA * 64 + w * 16 + quad * 4;
  const int qr0B = qB * 64 + w * 16 + quad * 4;

  // one q-tile's full body against the LDS-resident K/V tile j
  auto process = [&](const u16* Ksb, const u16* Vtb, int j, bf16x8 (&qa)[4],
                     f32x4 (&o)[8], float (&m_i)[4], float (&l_i)[4], int qrow0) {
    // S = Q K^T
    f32x4 s[4] = {};
    __builtin_amdgcn_s_setprio(1);
#pragma unroll
    for (int nb = 0; nb < 4; nb++) {
      int key = nb * 16 + col;
#pragma unroll
      for (int kk = 0; kk < 4; kk++) {
        bf16x8 kb2 = *(const bf16x8*)&Ksb[key * 128 + (((quad + 4 * kk) ^ col) << 3)];
        s[nb] = __builtin_amdgcn_mfma_f32_16x16x32_bf16(qa[kk], kb2, s[nb], 0, 0, 0);
      }
    }
    __builtin_amdgcn_s_setprio(0);

    // causal mask (self-gating: never true for j*64+63 < qrow0)
#pragma unroll
    for (int nb = 0; nb < 4; nb++)
#pragma unroll
      for (int rr = 0; rr < 4; rr++)
        if (j * 64 + nb * 16 + col > qrow0 + rr) s[nb][rr] = -3.0e38f;

    // online softmax; rows live across the 16 lanes of each quad
    float mnew[4];
#pragma unroll
    for (int rr = 0; rr < 4; rr++) {
      mnew[rr] = m_i[rr];
#pragma unroll
      for (int nb = 0; nb < 4; nb++) mnew[rr] = fmaxf(mnew[rr], s[nb][rr]);
    }
#pragma unroll
    for (int off = 1; off < 16; off <<= 1)
#pragma unroll
      for (int rr = 0; rr < 4; rr++)
        mnew[rr] = fmaxf(mnew[rr], __shfl_xor(mnew[rr], off));

    float p[4][4], rs[4], alpha[4];
#pragma unroll
    for (int rr = 0; rr < 4; rr++) {
      alpha[rr] = __builtin_exp2f((m_i[rr] - mnew[rr]) * cf);
      m_i[rr] = mnew[rr];
      rs[rr] = 0.0f;
    }
#pragma unroll
    for (int nb = 0; nb < 4; nb++)
#pragma unroll
      for (int rr = 0; rr < 4; rr++) {
        p[nb][rr] = __builtin_exp2f((s[nb][rr] - mnew[rr]) * cf);
        rs[rr] += p[nb][rr];
      }
#pragma unroll
    for (int off = 1; off < 16; off <<= 1)
#pragma unroll
      for (int rr = 0; rr < 4; rr++) rs[rr] += __shfl_xor(rs[rr], off);
#pragma unroll
    for (int rr = 0; rr < 4; rr++) l_i[rr] = l_i[rr] * alpha[rr] + rs[rr];
#pragma unroll
    for (int nb2 = 0; nb2 < 8; nb2++)
#pragma unroll
      for (int rr = 0; rr < 4; rr++) o[nb2][rr] *= alpha[rr];

    // P: C-layout -> LDS -> A-layout (per-wave slice; same-wave LDS in-order)
#pragma unroll
    for (int nb = 0; nb < 4; nb++)
#pragma unroll
      for (int rr = 0; rr < 4; rr++)
        Ps[w][quad * 4 + rr][nb * 16 + col] = f2bf(p[nb][rr]);

    bf16x8 pa0 = *(const bf16x8*)&Ps[w][col][quad * 8];
    bf16x8 pa1 = *(const bf16x8*)&Ps[w][col][quad * 8 + 32];
    __builtin_amdgcn_s_setprio(1);
#pragma unroll
    for (int nb2 = 0; nb2 < 8; nb2++) {
      int d = nb2 * 16 + col;
      bf16x8 vb0 = *(const bf16x8*)&Vtb[d * 64 + ((quad ^ (col & 7)) << 3)];
      bf16x8 vb1 = *(const bf16x8*)&Vtb[d * 64 + ((((quad + 4) & 7) ^ (col & 7)) << 3)];
      o[nb2] = __builtin_amdgcn_mfma_f32_16x16x32_bf16(pa0, vb0, o[nb2], 0, 0, 0);
      o[nb2] = __builtin_amdgcn_mfma_f32_16x16x32_bf16(pa1, vb1, o[nb2], 0, 0, 0);
    }
    __builtin_amdgcn_s_setprio(0);
  };

  for (int j = 0; j <= qB; j++) {
    const int bb = (j + 1) & 1;  // buffer holding tile j (tile0 -> buf1)
    if (j < qB) {
      stage_kv(bb ^ 1, j + 1);  // issue next tile; overlaps this tile's compute
      VMCNT(8);                 // tile j's 8 loads (oldest) complete
    } else {
      VMCNT(0);
    }
    BARRIER();  // all waves' tile-j stages landed

    const u16* Ksb = &Ks[bb][0];
    const u16* Vtb = &Vt[bb][0];

    if (j <= qA) process(Ksb, Vtb, j, qaA, oA, mA, lA, qr0A);
    process(Ksb, Vtb, j, qaB, oB, mB, lB, qr0B);

    BARRIER();  // all waves done reading buf bb before it's restaged
  }

  // epilogue: both tiles
#pragma unroll
  for (int rr = 0; rr < 4; rr++) {
    float invA = 1.0f / lA[rr];
    float invB = 1.0f / lB[rr];
#pragma unroll
    for (int nb2 = 0; nb2 < 8; nb2++) {
      size_t offA = (size_t)(b * 1024 + qA * 64 + w * 16 + quad * 4 + rr) * 4096 +
                    h * 128 + nb2 * 16 + col;
      size_t offB = (size_t)(b * 1024 + qB * 64 + w * 16 + quad * 4 + rr) * 4096 +
                    h * 128 + nb2 * 16 + col;
      Og[offA] = f2bf(oA[nb2][rr] * invA);
      Og[offB] = f2bf(oB[nb2][rr] * invB);
    }
  }
}

extern "C" void kernel_launch(void* const* d_in, const int* in_sizes, int n_in,
                              void* d_out, int out_size, void* d_ws, size_t ws_size,
                              hipStream_t stream) {
  const float* hs = (const float*)d_in[0];
  const float* wq = (const float*)d_in[1];
  const float* wk = (const float*)d_in[2];
  const float* wv = (const float*)d_in[3];
  const float* wo = (const float*)d_in[4];
  const int* pos = (const int*)d_in[6];
  float* out = (float*)d_out;

  char* ws = (char*)d_ws;
  const size_t MB = 1ull << 20;
  // Phase 1 layout:
  u16* hs_bf   = (u16*)(ws + 0);        // 32 MB [4096][4096]
  u16* wqkv_bf = (u16*)(ws + 32 * MB);  // 48 MB [6144][4096] (wq|wk|wv stacked)
  u16* QKV     = (u16*)(ws + 80 * MB);  // 48 MB [4096 tok][6144]: Q|K|V
  // Phase 2 layout (after QKV GEMM, hs_bf & wqkv_bf dead):
  u16* wo_bf = (u16*)(ws + 0);          // 32 MB
  u16* AOb   = (u16*)(ws + 32 * MB);    // 32 MB [4096][4096] attention out
  u16* VTb   = (u16*)(ws + 64 * MB);    // 8 MB  [1024 d][4096 tok]

  // converts: hs + stacked QKV weight
  cvt_kernel<<<16384, 256, 0, stream>>>(hs, hs_bf, 4194304);
  cvt_kernel<<<16384, 256, 0, stream>>>(wq, wqkv_bf, 4194304);
  cvt_kernel<<<4096, 256, 0, stream>>>(wk, wqkv_bf + 16777216, 1048576);
  cvt_kernel<<<4096, 256, 0, stream>>>(wv, wqkv_bf + 20971520, 1048576);

  // fused QKV projection: [4096][6144], 256^2 tiles, grid 24x16 = 384 blocks
  gemm8p<1><<<dim3(24, 16), 512, 0, stream>>>(hs_bf, wqkv_bf, QKV, 4096, 6144, 4096);

  // RoPE on Q (cols 0..4095) and K (cols 4096..5119), in place, stride 6144
  rope_kernel<<<32768, 256, 0, stream>>>(QKV, pos, 5, 6144);
  rope_kernel<<<8192, 256, 0, stream>>>(QKV + 4096, pos, 3, 6144);

  // V^T: transpose QKV[:, 5120:6144] -> VTb [1024][4096]
  transpose_kernel<<<dim3(16, 64), 256, 0, stream>>>(QKV + 5120, VTb, 6144, 4096);

  // convert wo (into dead hs_bf slot)
  cvt_kernel<<<16384, 256, 0, stream>>>(wo, wo_bf, 4194304);

  // attention: Q stride 6144, K stride 6144, V^T [1024][4096], QBLK=128
  attn_kernel<<<dim3(8, 32, 4), 256, 0, stream>>>(QKV, QKV + 4096, VTb, AOb, 6144, 6144);

  // output projection -> fp32 d_out
  gemm8p<0><<<dim3(16, 16), 512, 0, stream>>>(AOb, wo_bf, out, 4096, 4096, 4096);
}